// Round 3
// baseline (165.058 us; speedup 1.0000x reference)
//
#include <hip/hip_runtime.h>
#include <hip/hip_bf16.h>

#define NE 32
#define MM 1024
#define KK 512
#define NN 512
#define BM 64    // rows per tile
#define BN 128   // cols per tile -> 4 n-tiles
#define BK 32    // bf16 elems per LDS row = 64 B = 4 x 16B units, XOR-swizzled

typedef __attribute__((ext_vector_type(8))) short bf16x8;
typedef __attribute__((ext_vector_type(4))) float floatx4;

__device__ __forceinline__ short f2bf(float f) {
  union { __hip_bfloat16 b; short s; } u;
  u.b = __float2bfloat16(f);   // RNE
  return u.s;
}

// Persistent-block, XCD-partitioned schedule.
//   xcd = blockIdx.x & 7 (round-robin dispatch), slot0 = blockIdx.x >> 3 in [0,64)
//   XCD x owns experts {x, x+8, x+16, x+24}; items per expert (expert-major):
//     [4*vt GEMM tiles (mt-major, nt fastest)] ++ [(16-vt) zero 64x512 stripes]
//   Each block processes items slot0, slot0+64, slot0+128, ... (<= 4 rounds).
// Why: 64 resident slots/XCD keep the working front ~1.5 experts (~4.5 MiB),
// so cross-block A/B reuse is served by the 4 MiB XCD L2 (34 TB/s) instead of
// the L3 fabric (~7.5 TB/s) that round-2 counters showed to be the ceiling.
extern "C" __global__ __launch_bounds__(256, 2)
void expert_gemm(const float* __restrict__ A, const float* __restrict__ B,
                 const int* __restrict__ cnts, float* __restrict__ C)
{
  const int xcd   = blockIdx.x & 7;
  const int slot0 = blockIdx.x >> 3;   // 0..63
  const int tid   = threadIdx.x;

  // per-XCD expert item table (4 experts)
  int vt[4], base[5];
  base[0] = 0;
#pragma unroll
  for (int i = 0; i < 4; ++i) {
    vt[i] = (cnts[xcd + (i << 3)] + 63) >> 6;
    base[i + 1] = base[i] + 16 + 3 * vt[i];
  }
  const int total = base[4];   // <= 256

  __shared__ __align__(16) short lA[BM * BK];  // 4 KB
  __shared__ __align__(16) short lB[BN * BK];  // 8 KB

  const int wave = tid >> 6, lane = tid & 63;
  const int wm = (wave >> 1) * 32, wn = (wave & 1) * 64;  // wave tile: 32x64
  const int fr = lane & 15, kh = lane >> 4;
  const int sr = tid >> 2;   // staging row (A: row sr; B: rows sr and sr+64)
  const int su = tid & 3;    // 16B unit within row -> floats [su*8, su*8+8)

#pragma unroll 1
  for (int s = slot0; s < total; s += 64) {
    // decode item s -> (expert index i, residual r)
    int i = (s >= base[2]) ? ((s >= base[3]) ? 3 : 2) : ((s >= base[1]) ? 1 : 0);
    int r = s - base[i];
    const int e = xcd + (i << 3);
    const int v = vt[i];
    const int g = v << 2;

    if (r >= g) {
      // zero-fill a 64x512 stripe (harness poisons d_out each launch)
      int mt = v + (r - g);
      float* Ce = C + ((size_t)e * MM + mt * BM) * NN;
      float4 zf = make_float4(0.f, 0.f, 0.f, 0.f);
#pragma unroll
      for (int q = 0; q < 32; ++q) {
        int fidx = q * 256 + tid;
        int rr = fidx >> 7, cc = (fidx & 127) << 2;
        *(float4*)(Ce + (size_t)rr * NN + cc) = zf;
      }
      continue;
    }

    const int mt = r >> 2, nt = r & 3;
    const int m0 = mt * BM, n0 = nt * BN;
    const int cnt = cnts[e];
    const float* Ae = A + ((size_t)e * MM + m0) * KK;
    const float* Be = B + ((size_t)e * NN + n0) * KK;
    float* Ce = C + ((size_t)e * MM + m0) * NN + n0;

    floatx4 acc4[2][4] = {};

    // Register-prefetch double buffer (distance = 1 K-slab).
    float4 ra[2], rbv[4], na[2], nb[4];

#define ISSUE(pa, pb, kt_) do {                                          \
    int col_ = (kt_) + (su << 3);                                        \
    pa[0] = *(const float4*)(Ae + (size_t)sr * KK + col_);               \
    pa[1] = *(const float4*)(Ae + (size_t)sr * KK + col_ + 4);           \
    pb[0] = *(const float4*)(Be + (size_t)sr * KK + col_);               \
    pb[1] = *(const float4*)(Be + (size_t)sr * KK + col_ + 4);           \
    pb[2] = *(const float4*)(Be + (size_t)(sr + 64) * KK + col_);        \
    pb[3] = *(const float4*)(Be + (size_t)(sr + 64) * KK + col_ + 4);    \
  } while (0)

    ISSUE(ra, rbv, 0);

#pragma unroll
    for (int kt = 0; kt < KK; kt += BK) {
      if (kt + BK < KK) ISSUE(na, nb, kt + BK);   // static under full unroll

      // convert current slab (vmcnt wait lands here)
      bf16x8 va  = { f2bf(ra[0].x),  f2bf(ra[0].y),  f2bf(ra[0].z),  f2bf(ra[0].w),
                     f2bf(ra[1].x),  f2bf(ra[1].y),  f2bf(ra[1].z),  f2bf(ra[1].w) };
      bf16x8 vb0 = { f2bf(rbv[0].x), f2bf(rbv[0].y), f2bf(rbv[0].z), f2bf(rbv[0].w),
                     f2bf(rbv[1].x), f2bf(rbv[1].y), f2bf(rbv[1].z), f2bf(rbv[1].w) };
      bf16x8 vb1 = { f2bf(rbv[2].x), f2bf(rbv[2].y), f2bf(rbv[2].z), f2bf(rbv[2].w),
                     f2bf(rbv[3].x), f2bf(rbv[3].y), f2bf(rbv[3].z), f2bf(rbv[3].w) };

      __syncthreads();   // prior ds_reads (this item or previous item) complete
      {
        int u0 = (sr << 2) + (su ^ (sr & 3));
        *(bf16x8*)(lA + (u0 << 3)) = va;
        *(bf16x8*)(lB + (u0 << 3)) = vb0;
        int r1 = sr + 64;
        int u1 = (r1 << 2) + (su ^ (r1 & 3));
        *(bf16x8*)(lB + (u1 << 3)) = vb1;
      }
      __syncthreads();

      bf16x8 af[2], bfv[4];
#pragma unroll
      for (int q = 0; q < 2; ++q) {
        int rA = wm + (q << 4) + fr;
        af[q]  = *(const bf16x8*)(lA + ((((rA << 2) + (kh ^ (rA & 3)))) << 3));
      }
#pragma unroll
      for (int j = 0; j < 4; ++j) {
        int rB = wn + (j << 4) + fr;
        bfv[j] = *(const bf16x8*)(lB + ((((rB << 2) + (kh ^ (rB & 3)))) << 3));
      }
#pragma unroll
      for (int q = 0; q < 2; ++q)
#pragma unroll
        for (int j = 0; j < 4; ++j)
          acc4[q][j] = __builtin_amdgcn_mfma_f32_16x16x32_bf16(af[q], bfv[j], acc4[q][j], 0, 0, 0);

      // rotate prefetch buffers (renamed away by full unroll)
#pragma unroll
      for (int q = 0; q < 2; ++q) ra[q] = na[q];
#pragma unroll
      for (int q = 0; q < 4; ++q) rbv[q] = nb[q];
    }
#undef ISSUE

    // epilogue: C/D layout col=lane&15, row=(lane>>4)*4+reg (m89/m91-verified)
    const int rbase = (lane >> 4) * 4;
#pragma unroll
    for (int q = 0; q < 2; ++q) {
#pragma unroll
      for (int rr = 0; rr < 4; ++rr) {
        int row = wm + q * 16 + rbase + rr;
        bool valid = (m0 + row) < cnt;
#pragma unroll
        for (int j = 0; j < 4; ++j) {
          int col = wn + j * 16 + fr;
          Ce[(size_t)row * NN + col] = valid ? acc4[q][j][rr] : 0.0f;
        }
      }
    }
  }
}

extern "C" void kernel_launch(void* const* d_in, const int* in_sizes, int n_in,
                              void* d_out, int out_size, void* d_ws, size_t ws_size,
                              hipStream_t stream) {
  const float* A    = (const float*)d_in[0];
  const float* B    = (const float*)d_in[1];
  const int*   cnts = (const int*)d_in[2];
  float*       C    = (float*)d_out;

  // persistent: 512 blocks = 2/CU = 64 slots/XCD; each strides its XCD's items
  hipLaunchKernelGGL(expert_gemm, dim3(512), dim3(256), 0, stream, A, B, cnts, C);
}